// Round 5
// baseline (314.267 us; speedup 1.0000x reference)
//
#include <hip/hip_runtime.h>
#include <math.h>

#define NTOT (128*128*128)
#define NBIN2 64                 // bins per axis (2 cells per bin)
#define BINS (NBIN2*NBIN2*NBIN2) // 262144

// scatter tiles: 16 x 16 x 8 cells
#define TSX 16
#define TSY 16
#define TSZ 8
#define NTILES 1024
#define NSB 600                  // scanned bins per tile: 10*10*6
#define MAPCAP 3072

#define ZP 72                    // complex-mesh z pitch (>= 65, mult of 8)

#define PI_F      3.14159265358979323846f
#define TWO_PI_F  6.28318530717958647692f
#define FOUR_PI_F 12.5663706143591729539f

// skewed LDS index for FFT lines
#define IDX(i) ((i) + ((i) >> 5))
#define LDSW 132

// ---------- helpers ----------

__device__ inline void inv3x3(const float* __restrict__ c, float* inv, float* detOut) {
    float a = c[0], b = c[1], cc = c[2];
    float d = c[3], e = c[4], f  = c[5];
    float g = c[6], h = c[7], i  = c[8];
    float A = e * i - f * h;
    float B = f * g - d * i;
    float C = d * h - e * g;
    float det = a * A + b * B + cc * C;
    float r = 1.0f / det;
    inv[0] = A * r;              inv[1] = (cc * h - b * i) * r;  inv[2] = (b * f - cc * e) * r;
    inv[3] = B * r;              inv[4] = (a * i - cc * g) * r;  inv[5] = (cc * d - a * f) * r;
    inv[6] = C * r;              inv[7] = (b * g - a * h) * r;   inv[8] = (a * e - b * d) * r;
    *detOut = det;
}

__device__ inline void w4(float x, float* w) {
    float x2 = x * x, x3 = x2 * x;
    w[0] = (1.0f  - 6.0f  * x + 12.0f * x2 - 8.0f  * x3) * (1.0f / 48.0f);
    w[1] = (23.0f - 30.0f * x - 12.0f * x2 + 24.0f * x3) * (1.0f / 48.0f);
    w[2] = (23.0f + 30.0f * x - 12.0f * x2 - 24.0f * x3) * (1.0f / 48.0f);
    w[3] = (1.0f  + 6.0f  * x + 12.0f * x2 + 8.0f  * x3) * (1.0f / 48.0f);
}

__device__ inline void atom_rel(const float* __restrict__ cell,
                                const float* __restrict__ pos, int t,
                                float* rx, float* ry, float* rz) {
    float inv[9]; float det;
    inv3x3(cell, inv, &det);
    float px = pos[3 * t], py = pos[3 * t + 1], pz = pos[3 * t + 2];
    *rx = (px * inv[0] + py * inv[3] + pz * inv[6]) * 128.0f;
    *ry = (px * inv[1] + py * inv[4] + pz * inv[7]) * 128.0f;
    *rz = (px * inv[2] + py * inv[5] + pz * inv[8]) * 128.0f;
}

__device__ inline int bin_of(float rx, float ry, float rz) {
    int ix = ((int)floorf(rx)) & 127;
    int iy = ((int)floorf(ry)) & 127;
    int iz = ((int)floorf(rz)) & 127;
    return ((((ix >> 1) << 6) | (iy >> 1)) << 6) | (iz >> 1);
}

// ---------- binning ----------

__global__ void zero_int_kernel(int* __restrict__ p, int n) {
    int i = blockIdx.x * blockDim.x + threadIdx.x;
    if (i < n) p[i] = 0;
}

__global__ void hist_kernel(const float* __restrict__ cell, const float* __restrict__ pos,
                            int* __restrict__ hist, int n) {
    int t = blockIdx.x * blockDim.x + threadIdx.x;
    if (t >= n) return;
    float rx, ry, rz;
    atom_rel(cell, pos, t, &rx, &ry, &rz);
    atomicAdd(&hist[bin_of(rx, ry, rz)], 1);
}

// 1024 threads, int4 two-pass; writes offsets AND turns hist into the cursor.
__global__ __launch_bounds__(1024) void scan_kernel(int4* __restrict__ hist4,
                                                    int4* __restrict__ off4,
                                                    int* __restrict__ offsets) {
    const int t = threadIdx.x;
    const int base = t * 64;                 // 64 int4 = 256 bins per thread
    int s = 0;
    for (int i = 0; i < 64; ++i) {
        int4 h = hist4[base + i];
        s += h.x + h.y + h.z + h.w;
    }
    int lane = t & 63, wv = t >> 6;
    int v = s;
    #pragma unroll
    for (int d = 1; d < 64; d <<= 1) {
        int o = __shfl_up(v, d, 64);
        if (lane >= d) v += o;
    }
    __shared__ int wsum[16];
    if (lane == 63) wsum[wv] = v;
    __syncthreads();
    int add = 0;
    for (int k = 0; k < wv; ++k) add += wsum[k];
    int run = add + v - s;                   // exclusive prefix of this chunk
    for (int i = 0; i < 64; ++i) {
        int4 h = hist4[base + i];
        int4 o;
        o.x = run; run += h.x;
        o.y = run; run += h.y;
        o.z = run; run += h.z;
        o.w = run; run += h.w;
        off4[base + i]  = o;
        hist4[base + i] = o;                 // cursor for reorder
    }
    if (t == 1023) offsets[BINS] = run;
}

__global__ void reorder_kernel(const float* __restrict__ cell, const float* __restrict__ pos,
                               const float* __restrict__ q, int* __restrict__ cursor,
                               float4* __restrict__ sorted, int* __restrict__ sortedIdx, int n) {
    int t = blockIdx.x * blockDim.x + threadIdx.x;
    if (t >= n) return;
    float rx, ry, rz;
    atom_rel(cell, pos, t, &rx, &ry, &rz);
    int p = atomicAdd(&cursor[bin_of(rx, ry, rz)], 1);
    sorted[p] = make_float4(rx, ry, rz, q[t]);
    sortedIdx[p] = t;
}

// ---------- LDS-tiled scatter, flat work list, static-index stencil ----------

__global__ __launch_bounds__(512) void tile_scatter_kernel(const float4* __restrict__ atoms,
                                                           const int* __restrict__ offsets,
                                                           float* __restrict__ rmesh) {
    const int tile = blockIdx.x;             // 1024 tiles of 16x16x8 cells
    const int tz = tile & 15, ty = (tile >> 4) & 7, tx = tile >> 7;
    const int ox = tx << 4, oy = ty << 4, oz = tz << 3;

    __shared__ float acc[TSX * TSY * TSZ];   // [lx<<7 | ly<<3 | lz]
    __shared__ int P[NSB + 1];
    __shared__ int bstart[NSB];
    __shared__ int wsum[8];
    __shared__ unsigned short map[MAPCAP];

    const int t = threadIdx.x;
    for (int c = t; c < TSX * TSY * TSZ; c += 512) acc[c] = 0.0f;

    // bins: thread t < 300 owns s = 2t, 2t+1 of the 10x10x6 scan region
    int c0 = 0, c1 = 0;
    if (t < 300) {
        #pragma unroll
        for (int k = 0; k < 2; ++k) {
            int s  = 2 * t + k;
            int dx = s / 60, r = s - dx * 60;
            int dy = r / 6,  dz = r - dy * 6;
            int bx = (8 * tx - 1 + dx) & (NBIN2 - 1);
            int by = (8 * ty - 1 + dy) & (NBIN2 - 1);
            int bz = (4 * tz - 1 + dz) & (NBIN2 - 1);
            int bin = (((bx << 6) | by) << 6) | bz;
            int st  = offsets[bin];
            int cnt = offsets[bin + 1] - st;
            bstart[s] = st;
            if (k == 0) c0 = cnt; else c1 = cnt;
        }
    }
    int s = c0 + c1;
    int lane = t & 63, wv = t >> 6;
    int v = s;
    #pragma unroll
    for (int d = 1; d < 64; d <<= 1) {
        int o = __shfl_up(v, d, 64);
        if (lane >= d) v += o;
    }
    if (lane == 63) wsum[wv] = v;
    __syncthreads();
    int add = 0;
    for (int k = 0; k < wv; ++k) add += wsum[k];
    int run = add + v - s;
    if (t < 300) { P[2 * t] = run; P[2 * t + 1] = run + c0; }
    if (t == 299) P[NSB] = run + c0 + c1;
    __syncthreads();
    if (t < 300) {
        #pragma unroll
        for (int k = 0; k < 2; ++k) {
            int sb = 2 * t + k;
            int lo = P[sb], hi = P[sb + 1];
            if (hi > MAPCAP) hi = MAPCAP;
            for (int m = lo; m < hi; ++m) map[m] = (unsigned short)sb;
        }
    }
    __syncthreads();

    const int total = P[NSB];
    for (int i = t; i < total; i += 512) {
        int j;
        if (i < MAPCAP) {
            j = map[i];
        } else {                              // statistically never
            int lo = 0, hi = NSB - 1;
            while (lo < hi) { int mid = (lo + hi + 1) >> 1; if (P[mid] <= i) lo = mid; else hi = mid - 1; }
            j = lo;
        }
        float4 a = atoms[bstart[j] + (i - P[j])];

        float wx[4], wy[4], wz[4];
        int ax[4], ay[4], az[4];
        int vx = 0, vy = 0, vz = 0;
        {
            float fl = floorf(a.x); int i0 = (int)fl; float xx = a.x - fl - 0.5f; w4(xx, wx);
            #pragma unroll
            for (int s2 = 0; s2 < 4; ++s2) {
                int cc = (i0 + s2 - 1) & 127; int l = (cc - ox) & 127;
                int ok = (l < TSX); vx |= ok;
                ax[s2] = (l & (TSX - 1)) << 7;
                if (!ok) wx[s2] = 0.0f;
            }
        }
        {
            float fl = floorf(a.y); int i0 = (int)fl; float yy = a.y - fl - 0.5f; w4(yy, wy);
            #pragma unroll
            for (int s2 = 0; s2 < 4; ++s2) {
                int cc = (i0 + s2 - 1) & 127; int l = (cc - oy) & 127;
                int ok = (l < TSY); vy |= ok;
                ay[s2] = (l & (TSY - 1)) << 3;
                if (!ok) wy[s2] = 0.0f;
            }
        }
        {
            float fl = floorf(a.z); int i0 = (int)fl; float zz = a.z - fl - 0.5f; w4(zz, wz);
            #pragma unroll
            for (int s2 = 0; s2 < 4; ++s2) {
                int cc = (i0 + s2 - 1) & 127; int l = (cc - oz) & 127;
                int ok = (l < TSZ); vz |= ok;
                az[s2] = l & (TSZ - 1);
                if (!ok) wz[s2] = 0.0f;
            }
        }
        if (!(vx & vy & vz)) continue;
        float qc = a.w;
        #pragma unroll
        for (int i2 = 0; i2 < 4; ++i2) {
            float qx = qc * wx[i2];
            #pragma unroll
            for (int j2 = 0; j2 < 4; ++j2) {
                float qxy = qx * wy[j2];
                int bxy = ax[i2] | ay[j2];
                #pragma unroll
                for (int k2 = 0; k2 < 4; ++k2) {
                    float val = qxy * wz[k2];
                    if (val != 0.0f) atomicAdd(&acc[bxy | az[k2]], val);
                }
            }
        }
    }
    __syncthreads();

    for (int c = t; c < TSX * TSY * TSZ; c += 512) {
        int lx = c >> 7, ly = (c >> 3) & 15, lz = c & 7;
        int g = ((ox + lx) << 14) | ((oy + ly) << 7) | (oz + lz);
        rmesh[g] = acc[c];
    }
}

// ---------- FFT stage helpers (per-line, row w owned by wave w) ----------

template<int SIGN>
__device__ inline void dit7(float (*re)[LDSW], float (*im)[LDSW], int w, int lane) {
    #pragma unroll
    for (int s = 1; s <= 7; ++s) {
        int half = 1 << (s - 1);
        int pos = lane & (half - 1);
        int i = ((lane >> (s - 1)) << s) | pos;
        int j = i + half;
        float ang = (float)SIGN * PI_F * (float)pos / (float)half;
        float sn, cs; __sincosf(ang, &sn, &cs);
        int ii = IDX(i), jj = IDX(j);
        float ar = re[w][jj], ai = im[w][jj];
        float tr = cs * ar - sn * ai;
        float ti = cs * ai + sn * ar;
        float br = re[w][ii], bi = im[w][ii];
        re[w][jj] = br - tr; im[w][jj] = bi - ti;
        re[w][ii] = br + tr; im[w][ii] = bi + ti;
        __syncthreads();
    }
}

__device__ inline void dif7_fwd(float (*re)[LDSW], float (*im)[LDSW], int w, int lane) {
    #pragma unroll
    for (int s = 7; s >= 1; --s) {
        int half = 1 << (s - 1);
        int pos = lane & (half - 1);
        int i = ((lane >> (s - 1)) << s) | pos;
        int j = i + half;
        float ang = -PI_F * (float)pos / (float)half;
        float sn, cs; __sincosf(ang, &sn, &cs);
        int ii = IDX(i), jj = IDX(j);
        float ar = re[w][ii], ai = im[w][ii];
        float br = re[w][jj], bi = im[w][jj];
        re[w][ii] = ar + br;   im[w][ii] = ai + bi;
        float dr = ar - br, di = ai - bi;
        re[w][jj] = cs * dr - sn * di;
        im[w][jj] = cs * di + sn * dr;
        __syncthreads();
    }
}

// ---------- z forward: real -> complex (store zf < ZP), 16 lines/block ----------

__global__ __launch_bounds__(1024) void fftZfwd(const float* __restrict__ rin,
                                                float2* __restrict__ mesh) {
    __shared__ float re[16][LDSW], im[16][LDSW];
    const int t = threadIdx.x, b = blockIdx.x;
    for (int u = t; u < 2048; u += 1024) {
        int l = u >> 7, e = u & 127;
        float vv = rin[((size_t)((b << 4) | l) << 7) + e];
        int r = (int)(__brev((unsigned)e) >> 25);
        re[l][IDX(r)] = vv; im[l][IDX(r)] = 0.0f;
    }
    __syncthreads();
    const int w = t >> 6, lane = t & 63;
    dit7<-1>(re, im, w, lane);
    for (int u = t; u < 2048; u += 1024) {
        int l = u >> 7, e = u & 127;
        if (e < ZP)
            mesh[(size_t)((b << 4) | l) * ZP + e] = make_float2(re[l][IDX(e)], im[l][IDX(e)]);
    }
}

// ---------- y pass (c2c), 8 lines/block over zf chunk ----------

template<int SIGN>
__global__ __launch_bounds__(512) void fftY(float2* __restrict__ mesh) {
    __shared__ float re[8][LDSW], im[8][LDSW];
    const int t = threadIdx.x, b = blockIdx.x;
    const int x = b & 127, zf0 = (b >> 7) << 3;
    for (int u = t; u < 1024; u += 512) {
        int l = u & 7, e = u >> 3;
        float2 v = mesh[(size_t)((x << 7) | e) * ZP + zf0 + l];
        int r = (int)(__brev((unsigned)e) >> 25);
        re[l][IDX(r)] = v.x; im[l][IDX(r)] = v.y;
    }
    __syncthreads();
    const int w = t >> 6, lane = t & 63;
    dit7<SIGN>(re, im, w, lane);
    for (int u = t; u < 1024; u += 512) {
        int l = u & 7, e = u >> 3;
        mesh[(size_t)((x << 7) | e) * ZP + zf0 + l] = make_float2(re[l][IDX(e)], im[l][IDX(e)]);
    }
}

// ---------- fused x: forward DIF -> G(k) (bit-reversed) -> inverse DIT ----------

__global__ __launch_bounds__(512) void fftXG(float2* __restrict__ mesh,
                                             const float* __restrict__ cell) {
    __shared__ float re[8][LDSW], im[8][LDSW];
    const int t = threadIdx.x, b = blockIdx.x;
    const int y = b & 127, zf0 = (b >> 7) << 3;
    for (int u = t; u < 1024; u += 512) {
        int l = u & 7, e = u >> 3;
        float2 v = mesh[(size_t)((e << 7) | y) * ZP + zf0 + l];
        re[l][IDX(e)] = v.x; im[l][IDX(e)] = v.y;
    }
    __syncthreads();
    const int w = t >> 6, lane = t & 63;
    dif7_fwd(re, im, w, lane);
    {
        float inv[9]; float det; inv3x3(cell, inv, &det);
        float invVol = 1.0f / fabsf(det);
        int my = y, mz = zf0 + w;
        float fy = (my < 64) ? (float)my : (float)(my - 128);
        float fz = (mz < 64) ? (float)mz : (float)(mz - 128);
        for (int p = lane; p < 128; p += 64) {
            int mx = (int)(__brev((unsigned)p) >> 25);
            float fx = (mx < 64) ? (float)mx : (float)(mx - 128);
            float kx = TWO_PI_F * (fx * inv[0] + fy * inv[1] + fz * inv[2]);
            float ky = TWO_PI_F * (fx * inv[3] + fy * inv[4] + fz * inv[5]);
            float kz = TWO_PI_F * (fx * inv[6] + fy * inv[7] + fz * inv[8]);
            float ksq = kx * kx + ky * ky + kz * kz;
            float G = (ksq == 0.0f) ? 0.0f
                      : FOUR_PI_F / ksq * __expf(-0.5f * ksq) * invVol;
            re[w][IDX(p)] *= G; im[w][IDX(p)] *= G;
        }
    }
    __syncthreads();
    dit7<1>(re, im, w, lane);
    for (int u = t; u < 1024; u += 512) {
        int l = u & 7, e = u >> 3;
        mesh[(size_t)((e << 7) | y) * ZP + zf0 + l] = make_float2(re[l][IDX(e)], im[l][IDX(e)]);
    }
}

// ---------- z inverse: Hermitian mirror -> real out, 16 lines/block ----------

__global__ __launch_bounds__(1024) void fftZinv(const float2* __restrict__ mesh,
                                                float* __restrict__ rout) {
    __shared__ float re[16][LDSW], im[16][LDSW];
    const int t = threadIdx.x, b = blockIdx.x;
    for (int u = t; u < 2048; u += 1024) {
        int l = u >> 7, e = u & 127;
        int src = (e <= 64) ? e : 128 - e;
        float2 v = mesh[(size_t)((b << 4) | l) * ZP + src];
        float vy = (e <= 64) ? v.y : -v.y;
        int r = (int)(__brev((unsigned)e) >> 25);
        re[l][IDX(r)] = v.x; im[l][IDX(r)] = vy;
    }
    __syncthreads();
    const int w = t >> 6, lane = t & 63;
    dit7<1>(re, im, w, lane);
    for (int u = t; u < 2048; u += 1024) {
        int l = u >> 7, e = u & 127;
        rout[((size_t)((b << 4) | l) << 7) + e] = re[l][IDX(e)];
    }
}

// ---------- gather ----------

__global__ void gather_kernel(const float4* __restrict__ sorted, const int* __restrict__ sortedIdx,
                              const float* __restrict__ rmesh, float* __restrict__ out, int n) {
    int t = blockIdx.x * blockDim.x + threadIdx.x;
    if (t >= n) return;
    float4 a = sorted[t];
    float wx[4], wy[4], wz[4];
    int ix[4], iy[4], iz[4];
    {
        float fl = floorf(a.x); int i0 = (int)fl; float x = a.x - fl - 0.5f; w4(x, wx);
        #pragma unroll
        for (int s = 0; s < 4; ++s) ix[s] = (i0 + s - 1) & 127;
    }
    {
        float fl = floorf(a.y); int i0 = (int)fl; float x = a.y - fl - 0.5f; w4(x, wy);
        #pragma unroll
        for (int s = 0; s < 4; ++s) iy[s] = (i0 + s - 1) & 127;
    }
    {
        float fl = floorf(a.z); int i0 = (int)fl; float x = a.z - fl - 0.5f; w4(x, wz);
        #pragma unroll
        for (int s = 0; s < 4; ++s) iz[s] = (i0 + s - 1) & 127;
    }
    float sum = 0.0f;
    #pragma unroll
    for (int i = 0; i < 4; ++i) {
        int bx = ix[i] << 14;
        float acc_i = 0.0f;
        #pragma unroll
        for (int j = 0; j < 4; ++j) {
            int bxy = bx | (iy[j] << 7);
            float acc_j = 0.0f;
            #pragma unroll
            for (int k = 0; k < 4; ++k) {
                acc_j += wz[k] * rmesh[bxy | iz[k]];
            }
            acc_i += wy[j] * acc_j;
        }
        sum += wx[i] * acc_i;
    }
    out[sortedIdx[t]] = sum - a.w * 0.79788456080286535588f;
}

// ---------- launch ----------

extern "C" void kernel_launch(void* const* d_in, const int* in_sizes, int n_in,
                              void* d_out, int out_size, void* d_ws, size_t ws_size,
                              hipStream_t stream) {
    const float* cell = (const float*)d_in[0];
    const float* pos  = (const float*)d_in[1];
    const float* q    = (const float*)d_in[2];
    float* out = (float*)d_out;
    const int n = in_sizes[2];

    char* ws = (char*)d_ws;
    size_t o = 0;
    float4* sorted   = (float4*)(ws + o); o += (size_t)n * 16;
    int* sortedIdx   = (int*)(ws + o);    o += (size_t)n * 4;  o = (o + 255) & ~(size_t)255;
    int* hist        = (int*)(ws + o);    o += (size_t)BINS * 4;            // also reorder cursor
    int* offsets     = (int*)(ws + o);    o += (size_t)(BINS + 4) * 4; o = (o + 255) & ~(size_t)255;
    float2* mesh     = (float2*)(ws + o); o += (size_t)128 * 128 * ZP * 8;  // 9.4 MB
    float* rmesh     = (float*)(ws + o);  // NTOT * 4 = 8 MB

    zero_int_kernel<<<BINS / 256, 256, 0, stream>>>(hist, BINS);
    hist_kernel<<<(n + 255) / 256, 256, 0, stream>>>(cell, pos, hist, n);
    scan_kernel<<<1, 1024, 0, stream>>>((int4*)hist, (int4*)offsets, offsets);
    reorder_kernel<<<(n + 255) / 256, 256, 0, stream>>>(cell, pos, q, hist, sorted, sortedIdx, n);
    tile_scatter_kernel<<<NTILES, 512, 0, stream>>>(sorted, offsets, rmesh);

    fftZfwd<<<1024, 1024, 0, stream>>>(rmesh, mesh);
    fftY<-1><<<9 * 128, 512, 0, stream>>>(mesh);
    fftXG<<<9 * 128, 512, 0, stream>>>(mesh, cell);
    fftY<1><<<9 * 128, 512, 0, stream>>>(mesh);
    fftZinv<<<1024, 1024, 0, stream>>>(mesh, rmesh);

    gather_kernel<<<(n + 255) / 256, 256, 0, stream>>>(sorted, sortedIdx, rmesh, out, n);
}

// Round 6
// 183.591 us; speedup vs baseline: 1.7118x; 1.7118x over previous
//
#include <hip/hip_runtime.h>
#include <math.h>

#define NTOT (128*128*128)
#define NBIN2 64                 // bins per axis (2 cells per bin)
#define BINS (NBIN2*NBIN2*NBIN2) // 262144
#define SCAN_BLOCKS 256          // hierarchical scan: 256 blocks x 1024 bins

// scatter tiles: 16 x 16 x 8 cells
#define TSX 16
#define TSY 16
#define TSZ 8
#define NTILES 1024
#define NSB 600                  // scanned bins per tile: 10*10*6
#define MAPCAP 3072

#define ZP 72                    // complex-mesh z pitch (>= 65, mult of 8)

#define PI_F      3.14159265358979323846f
#define TWO_PI_F  6.28318530717958647692f
#define FOUR_PI_F 12.5663706143591729539f

// skewed LDS index for FFT lines
#define IDX(i) ((i) + ((i) >> 5))
#define LDSW 132

// ---------- helpers ----------

__device__ inline void inv3x3(const float* __restrict__ c, float* inv, float* detOut) {
    float a = c[0], b = c[1], cc = c[2];
    float d = c[3], e = c[4], f  = c[5];
    float g = c[6], h = c[7], i  = c[8];
    float A = e * i - f * h;
    float B = f * g - d * i;
    float C = d * h - e * g;
    float det = a * A + b * B + cc * C;
    float r = 1.0f / det;
    inv[0] = A * r;              inv[1] = (cc * h - b * i) * r;  inv[2] = (b * f - cc * e) * r;
    inv[3] = B * r;              inv[4] = (a * i - cc * g) * r;  inv[5] = (cc * d - a * f) * r;
    inv[6] = C * r;              inv[7] = (b * g - a * h) * r;   inv[8] = (a * e - b * d) * r;
    *detOut = det;
}

__device__ inline void w4(float x, float* w) {
    float x2 = x * x, x3 = x2 * x;
    w[0] = (1.0f  - 6.0f  * x + 12.0f * x2 - 8.0f  * x3) * (1.0f / 48.0f);
    w[1] = (23.0f - 30.0f * x - 12.0f * x2 + 24.0f * x3) * (1.0f / 48.0f);
    w[2] = (23.0f + 30.0f * x - 12.0f * x2 - 24.0f * x3) * (1.0f / 48.0f);
    w[3] = (1.0f  + 6.0f  * x + 12.0f * x2 + 8.0f  * x3) * (1.0f / 48.0f);
}

__device__ inline void atom_rel(const float* __restrict__ cell,
                                const float* __restrict__ pos, int t,
                                float* rx, float* ry, float* rz) {
    float inv[9]; float det;
    inv3x3(cell, inv, &det);
    float px = pos[3 * t], py = pos[3 * t + 1], pz = pos[3 * t + 2];
    *rx = (px * inv[0] + py * inv[3] + pz * inv[6]) * 128.0f;
    *ry = (px * inv[1] + py * inv[4] + pz * inv[7]) * 128.0f;
    *rz = (px * inv[2] + py * inv[5] + pz * inv[8]) * 128.0f;
}

__device__ inline int bin_of(float rx, float ry, float rz) {
    int ix = ((int)floorf(rx)) & 127;
    int iy = ((int)floorf(ry)) & 127;
    int iz = ((int)floorf(rz)) & 127;
    return ((((ix >> 1) << 6) | (iy >> 1)) << 6) | (iz >> 1);
}

// ---------- binning ----------

__global__ void zero_int_kernel(int* __restrict__ p, int n) {
    int i = blockIdx.x * blockDim.x + threadIdx.x;
    if (i < n) p[i] = 0;
}

__global__ void hist_kernel(const float* __restrict__ cell, const float* __restrict__ pos,
                            int* __restrict__ hist, int n) {
    int t = blockIdx.x * blockDim.x + threadIdx.x;
    if (t >= n) return;
    float rx, ry, rz;
    atom_rel(cell, pos, t, &rx, &ry, &rz);
    atomicAdd(&hist[bin_of(rx, ry, rz)], 1);
}

// phase 1: per-block exclusive scan of 1024 bins (256 threads x int4), block totals
__global__ __launch_bounds__(256) void scan_local(const int4* __restrict__ hist4,
                                                  int4* __restrict__ off4,
                                                  int* __restrict__ partials) {
    const int b = blockIdx.x, t = threadIdx.x;
    const int idx = b * 256 + t;
    int4 h = hist4[idx];
    int s = h.x + h.y + h.z + h.w;
    int lane = t & 63, wv = t >> 6;
    int v = s;
    #pragma unroll
    for (int d = 1; d < 64; d <<= 1) {
        int o = __shfl_up(v, d, 64);
        if (lane >= d) v += o;
    }
    __shared__ int wsum[4];
    if (lane == 63) wsum[wv] = v;
    __syncthreads();
    int add = 0;
    #pragma unroll
    for (int k = 0; k < 4; ++k) if (k < wv) add += wsum[k];
    int run = add + v - s;                  // exclusive prefix within block
    int4 o4;
    o4.x = run; run += h.x;
    o4.y = run; run += h.y;
    o4.z = run; run += h.z;
    o4.w = run; run += h.w;                 // run = inclusive
    off4[idx] = o4;
    if (t == 255) partials[b] = run;        // block total
}

// phase 2: add block base; write offsets AND cursor (hist4)
__global__ __launch_bounds__(256) void scan_add(int4* __restrict__ hist4,
                                                int4* __restrict__ off4,
                                                const int* __restrict__ partials,
                                                int* __restrict__ offsets) {
    const int b = blockIdx.x, t = threadIdx.x;
    int lane = t & 63, wv = t >> 6;
    int v = (t < b) ? partials[t] : 0;
    #pragma unroll
    for (int d = 32; d >= 1; d >>= 1) v += __shfl_xor(v, d, 64);
    __shared__ int ws2[4];
    __shared__ int base_s;
    if (lane == 0) ws2[wv] = v;
    __syncthreads();
    if (t == 0) base_s = ws2[0] + ws2[1] + ws2[2] + ws2[3];
    __syncthreads();
    const int base = base_s;
    const int idx = b * 256 + t;
    int4 o4 = off4[idx];
    o4.x += base; o4.y += base; o4.z += base; o4.w += base;
    off4[idx]  = o4;
    hist4[idx] = o4;                        // reorder cursor
    if (b == SCAN_BLOCKS - 1 && t == 255) offsets[BINS] = base + partials[b];
}

__global__ void reorder_kernel(const float* __restrict__ cell, const float* __restrict__ pos,
                               const float* __restrict__ q, int* __restrict__ cursor,
                               float4* __restrict__ sorted, int* __restrict__ sortedIdx, int n) {
    int t = blockIdx.x * blockDim.x + threadIdx.x;
    if (t >= n) return;
    float rx, ry, rz;
    atom_rel(cell, pos, t, &rx, &ry, &rz);
    int p = atomicAdd(&cursor[bin_of(rx, ry, rz)], 1);
    sorted[p] = make_float4(rx, ry, rz, q[t]);
    sortedIdx[p] = t;
}

// ---------- LDS-tiled scatter, flat work list, static-index stencil ----------

__global__ __launch_bounds__(512) void tile_scatter_kernel(const float4* __restrict__ atoms,
                                                           const int* __restrict__ offsets,
                                                           float* __restrict__ rmesh) {
    const int tile = blockIdx.x;             // 1024 tiles of 16x16x8 cells
    const int tz = tile & 15, ty = (tile >> 4) & 7, tx = tile >> 7;
    const int ox = tx << 4, oy = ty << 4, oz = tz << 3;

    __shared__ float acc[TSX * TSY * TSZ];   // [lx<<7 | ly<<3 | lz]
    __shared__ int P[NSB + 1];
    __shared__ int bstart[NSB];
    __shared__ int wsum[8];
    __shared__ unsigned short map[MAPCAP];

    const int t = threadIdx.x;
    for (int c = t; c < TSX * TSY * TSZ; c += 512) acc[c] = 0.0f;

    // bins: thread t < 300 owns s = 2t, 2t+1 of the 10x10x6 scan region
    int c0 = 0, c1 = 0;
    if (t < 300) {
        #pragma unroll
        for (int k = 0; k < 2; ++k) {
            int s  = 2 * t + k;
            int dx = s / 60, r = s - dx * 60;
            int dy = r / 6,  dz = r - dy * 6;
            int bx = (8 * tx - 1 + dx) & (NBIN2 - 1);
            int by = (8 * ty - 1 + dy) & (NBIN2 - 1);
            int bz = (4 * tz - 1 + dz) & (NBIN2 - 1);
            int bin = (((bx << 6) | by) << 6) | bz;
            int st  = offsets[bin];
            int cnt = offsets[bin + 1] - st;
            bstart[s] = st;
            if (k == 0) c0 = cnt; else c1 = cnt;
        }
    }
    int s = c0 + c1;
    int lane = t & 63, wv = t >> 6;
    int v = s;
    #pragma unroll
    for (int d = 1; d < 64; d <<= 1) {
        int o = __shfl_up(v, d, 64);
        if (lane >= d) v += o;
    }
    if (lane == 63) wsum[wv] = v;
    __syncthreads();
    int add = 0;
    for (int k = 0; k < wv; ++k) add += wsum[k];
    int run = add + v - s;
    if (t < 300) { P[2 * t] = run; P[2 * t + 1] = run + c0; }
    if (t == 299) P[NSB] = run + c0 + c1;
    __syncthreads();
    if (t < 300) {
        #pragma unroll
        for (int k = 0; k < 2; ++k) {
            int sb = 2 * t + k;
            int lo = P[sb], hi = P[sb + 1];
            if (hi > MAPCAP) hi = MAPCAP;
            for (int m = lo; m < hi; ++m) map[m] = (unsigned short)sb;
        }
    }
    __syncthreads();

    const int total = P[NSB];
    for (int i = t; i < total; i += 512) {
        int j;
        if (i < MAPCAP) {
            j = map[i];
        } else {                              // statistically never
            int lo = 0, hi = NSB - 1;
            while (lo < hi) { int mid = (lo + hi + 1) >> 1; if (P[mid] <= i) lo = mid; else hi = mid - 1; }
            j = lo;
        }
        float4 a = atoms[bstart[j] + (i - P[j])];

        float wx[4], wy[4], wz[4];
        int ax[4], ay[4], az[4];
        int vx = 0, vy = 0, vz = 0;
        {
            float fl = floorf(a.x); int i0 = (int)fl; float xx = a.x - fl - 0.5f; w4(xx, wx);
            #pragma unroll
            for (int s2 = 0; s2 < 4; ++s2) {
                int cc = (i0 + s2 - 1) & 127; int l = (cc - ox) & 127;
                int ok = (l < TSX); vx |= ok;
                ax[s2] = (l & (TSX - 1)) << 7;
                if (!ok) wx[s2] = 0.0f;
            }
        }
        {
            float fl = floorf(a.y); int i0 = (int)fl; float yy = a.y - fl - 0.5f; w4(yy, wy);
            #pragma unroll
            for (int s2 = 0; s2 < 4; ++s2) {
                int cc = (i0 + s2 - 1) & 127; int l = (cc - oy) & 127;
                int ok = (l < TSY); vy |= ok;
                ay[s2] = (l & (TSY - 1)) << 3;
                if (!ok) wy[s2] = 0.0f;
            }
        }
        {
            float fl = floorf(a.z); int i0 = (int)fl; float zz = a.z - fl - 0.5f; w4(zz, wz);
            #pragma unroll
            for (int s2 = 0; s2 < 4; ++s2) {
                int cc = (i0 + s2 - 1) & 127; int l = (cc - oz) & 127;
                int ok = (l < TSZ); vz |= ok;
                az[s2] = l & (TSZ - 1);
                if (!ok) wz[s2] = 0.0f;
            }
        }
        if (!(vx & vy & vz)) continue;
        float qc = a.w;
        #pragma unroll
        for (int i2 = 0; i2 < 4; ++i2) {
            float qx = qc * wx[i2];
            #pragma unroll
            for (int j2 = 0; j2 < 4; ++j2) {
                float qxy = qx * wy[j2];
                int bxy = ax[i2] | ay[j2];
                #pragma unroll
                for (int k2 = 0; k2 < 4; ++k2) {
                    float val = qxy * wz[k2];
                    if (val != 0.0f) atomicAdd(&acc[bxy | az[k2]], val);
                }
            }
        }
    }
    __syncthreads();

    for (int c = t; c < TSX * TSY * TSZ; c += 512) {
        int lx = c >> 7, ly = (c >> 3) & 15, lz = c & 7;
        int g = ((ox + lx) << 14) | ((oy + ly) << 7) | (oz + lz);
        rmesh[g] = acc[c];
    }
}

// ---------- FFT stage helpers (per-line, row w owned by wave w) ----------

template<int SIGN>
__device__ inline void dit7(float (*re)[LDSW], float (*im)[LDSW], int w, int lane) {
    #pragma unroll
    for (int s = 1; s <= 7; ++s) {
        int half = 1 << (s - 1);
        int pos = lane & (half - 1);
        int i = ((lane >> (s - 1)) << s) | pos;
        int j = i + half;
        float ang = (float)SIGN * PI_F * (float)pos / (float)half;
        float sn, cs; __sincosf(ang, &sn, &cs);
        int ii = IDX(i), jj = IDX(j);
        float ar = re[w][jj], ai = im[w][jj];
        float tr = cs * ar - sn * ai;
        float ti = cs * ai + sn * ar;
        float br = re[w][ii], bi = im[w][ii];
        re[w][jj] = br - tr; im[w][jj] = bi - ti;
        re[w][ii] = br + tr; im[w][ii] = bi + ti;
        __syncthreads();
    }
}

__device__ inline void dif7_fwd(float (*re)[LDSW], float (*im)[LDSW], int w, int lane) {
    #pragma unroll
    for (int s = 7; s >= 1; --s) {
        int half = 1 << (s - 1);
        int pos = lane & (half - 1);
        int i = ((lane >> (s - 1)) << s) | pos;
        int j = i + half;
        float ang = -PI_F * (float)pos / (float)half;
        float sn, cs; __sincosf(ang, &sn, &cs);
        int ii = IDX(i), jj = IDX(j);
        float ar = re[w][ii], ai = im[w][ii];
        float br = re[w][jj], bi = im[w][jj];
        re[w][ii] = ar + br;   im[w][ii] = ai + bi;
        float dr = ar - br, di = ai - bi;
        re[w][jj] = cs * dr - sn * di;
        im[w][jj] = cs * di + sn * dr;
        __syncthreads();
    }
}

// ---------- z forward: real -> complex (store zf < ZP), 16 lines/block ----------

__global__ __launch_bounds__(1024) void fftZfwd(const float* __restrict__ rin,
                                                float2* __restrict__ mesh) {
    __shared__ float re[16][LDSW], im[16][LDSW];
    const int t = threadIdx.x, b = blockIdx.x;
    for (int u = t; u < 2048; u += 1024) {
        int l = u >> 7, e = u & 127;
        float vv = rin[((size_t)((b << 4) | l) << 7) + e];
        int r = (int)(__brev((unsigned)e) >> 25);
        re[l][IDX(r)] = vv; im[l][IDX(r)] = 0.0f;
    }
    __syncthreads();
    const int w = t >> 6, lane = t & 63;
    dit7<-1>(re, im, w, lane);
    for (int u = t; u < 2048; u += 1024) {
        int l = u >> 7, e = u & 127;
        if (e < ZP)
            mesh[(size_t)((b << 4) | l) * ZP + e] = make_float2(re[l][IDX(e)], im[l][IDX(e)]);
    }
}

// ---------- y pass (c2c), 8 lines/block over zf chunk ----------

template<int SIGN>
__global__ __launch_bounds__(512) void fftY(float2* __restrict__ mesh) {
    __shared__ float re[8][LDSW], im[8][LDSW];
    const int t = threadIdx.x, b = blockIdx.x;
    const int x = b & 127, zf0 = (b >> 7) << 3;
    for (int u = t; u < 1024; u += 512) {
        int l = u & 7, e = u >> 3;
        float2 v = mesh[(size_t)((x << 7) | e) * ZP + zf0 + l];
        int r = (int)(__brev((unsigned)e) >> 25);
        re[l][IDX(r)] = v.x; im[l][IDX(r)] = v.y;
    }
    __syncthreads();
    const int w = t >> 6, lane = t & 63;
    dit7<SIGN>(re, im, w, lane);
    for (int u = t; u < 1024; u += 512) {
        int l = u & 7, e = u >> 3;
        mesh[(size_t)((x << 7) | e) * ZP + zf0 + l] = make_float2(re[l][IDX(e)], im[l][IDX(e)]);
    }
}

// ---------- fused x: forward DIF -> G(k) (bit-reversed) -> inverse DIT ----------

__global__ __launch_bounds__(512) void fftXG(float2* __restrict__ mesh,
                                             const float* __restrict__ cell) {
    __shared__ float re[8][LDSW], im[8][LDSW];
    const int t = threadIdx.x, b = blockIdx.x;
    const int y = b & 127, zf0 = (b >> 7) << 3;
    for (int u = t; u < 1024; u += 512) {
        int l = u & 7, e = u >> 3;
        float2 v = mesh[(size_t)((e << 7) | y) * ZP + zf0 + l];
        re[l][IDX(e)] = v.x; im[l][IDX(e)] = v.y;
    }
    __syncthreads();
    const int w = t >> 6, lane = t & 63;
    dif7_fwd(re, im, w, lane);
    {
        float inv[9]; float det; inv3x3(cell, inv, &det);
        float invVol = 1.0f / fabsf(det);
        int my = y, mz = zf0 + w;
        float fy = (my < 64) ? (float)my : (float)(my - 128);
        float fz = (mz < 64) ? (float)mz : (float)(mz - 128);
        for (int p = lane; p < 128; p += 64) {
            int mx = (int)(__brev((unsigned)p) >> 25);
            float fx = (mx < 64) ? (float)mx : (float)(mx - 128);
            float kx = TWO_PI_F * (fx * inv[0] + fy * inv[1] + fz * inv[2]);
            float ky = TWO_PI_F * (fx * inv[3] + fy * inv[4] + fz * inv[5]);
            float kz = TWO_PI_F * (fx * inv[6] + fy * inv[7] + fz * inv[8]);
            float ksq = kx * kx + ky * ky + kz * kz;
            float G = (ksq == 0.0f) ? 0.0f
                      : FOUR_PI_F / ksq * __expf(-0.5f * ksq) * invVol;
            re[w][IDX(p)] *= G; im[w][IDX(p)] *= G;
        }
    }
    __syncthreads();
    dit7<1>(re, im, w, lane);
    for (int u = t; u < 1024; u += 512) {
        int l = u & 7, e = u >> 3;
        mesh[(size_t)((e << 7) | y) * ZP + zf0 + l] = make_float2(re[l][IDX(e)], im[l][IDX(e)]);
    }
}

// ---------- z inverse: Hermitian mirror -> real out, 16 lines/block ----------

__global__ __launch_bounds__(1024) void fftZinv(const float2* __restrict__ mesh,
                                                float* __restrict__ rout) {
    __shared__ float re[16][LDSW], im[16][LDSW];
    const int t = threadIdx.x, b = blockIdx.x;
    for (int u = t; u < 2048; u += 1024) {
        int l = u >> 7, e = u & 127;
        int src = (e <= 64) ? e : 128 - e;
        float2 v = mesh[(size_t)((b << 4) | l) * ZP + src];
        float vy = (e <= 64) ? v.y : -v.y;
        int r = (int)(__brev((unsigned)e) >> 25);
        re[l][IDX(r)] = v.x; im[l][IDX(r)] = vy;
    }
    __syncthreads();
    const int w = t >> 6, lane = t & 63;
    dit7<1>(re, im, w, lane);
    for (int u = t; u < 2048; u += 1024) {
        int l = u >> 7, e = u & 127;
        rout[((size_t)((b << 4) | l) << 7) + e] = re[l][IDX(e)];
    }
}

// ---------- gather ----------

__global__ void gather_kernel(const float4* __restrict__ sorted, const int* __restrict__ sortedIdx,
                              const float* __restrict__ rmesh, float* __restrict__ out, int n) {
    int t = blockIdx.x * blockDim.x + threadIdx.x;
    if (t >= n) return;
    float4 a = sorted[t];
    float wx[4], wy[4], wz[4];
    int ix[4], iy[4], iz[4];
    {
        float fl = floorf(a.x); int i0 = (int)fl; float x = a.x - fl - 0.5f; w4(x, wx);
        #pragma unroll
        for (int s = 0; s < 4; ++s) ix[s] = (i0 + s - 1) & 127;
    }
    {
        float fl = floorf(a.y); int i0 = (int)fl; float x = a.y - fl - 0.5f; w4(x, wy);
        #pragma unroll
        for (int s = 0; s < 4; ++s) iy[s] = (i0 + s - 1) & 127;
    }
    {
        float fl = floorf(a.z); int i0 = (int)fl; float x = a.z - fl - 0.5f; w4(x, wz);
        #pragma unroll
        for (int s = 0; s < 4; ++s) iz[s] = (i0 + s - 1) & 127;
    }
    float sum = 0.0f;
    #pragma unroll
    for (int i = 0; i < 4; ++i) {
        int bx = ix[i] << 14;
        float acc_i = 0.0f;
        #pragma unroll
        for (int j = 0; j < 4; ++j) {
            int bxy = bx | (iy[j] << 7);
            float acc_j = 0.0f;
            #pragma unroll
            for (int k = 0; k < 4; ++k) {
                acc_j += wz[k] * rmesh[bxy | iz[k]];
            }
            acc_i += wy[j] * acc_j;
        }
        sum += wx[i] * acc_i;
    }
    out[sortedIdx[t]] = sum - a.w * 0.79788456080286535588f;
}

// ---------- launch ----------

extern "C" void kernel_launch(void* const* d_in, const int* in_sizes, int n_in,
                              void* d_out, int out_size, void* d_ws, size_t ws_size,
                              hipStream_t stream) {
    const float* cell = (const float*)d_in[0];
    const float* pos  = (const float*)d_in[1];
    const float* q    = (const float*)d_in[2];
    float* out = (float*)d_out;
    const int n = in_sizes[2];

    char* ws = (char*)d_ws;
    size_t o = 0;
    float4* sorted   = (float4*)(ws + o); o += (size_t)n * 16;
    int* sortedIdx   = (int*)(ws + o);    o += (size_t)n * 4;  o = (o + 255) & ~(size_t)255;
    int* hist        = (int*)(ws + o);    o += (size_t)BINS * 4;            // also reorder cursor
    int* offsets     = (int*)(ws + o);    o += (size_t)(BINS + 4) * 4;
    int* partials    = (int*)(ws + o);    o += (size_t)SCAN_BLOCKS * 4; o = (o + 255) & ~(size_t)255;
    float2* mesh     = (float2*)(ws + o); o += (size_t)128 * 128 * ZP * 8;  // 9.4 MB
    float* rmesh     = (float*)(ws + o);  // NTOT * 4 = 8 MB

    zero_int_kernel<<<BINS / 256, 256, 0, stream>>>(hist, BINS);
    hist_kernel<<<(n + 255) / 256, 256, 0, stream>>>(cell, pos, hist, n);
    scan_local<<<SCAN_BLOCKS, 256, 0, stream>>>((const int4*)hist, (int4*)offsets, partials);
    scan_add<<<SCAN_BLOCKS, 256, 0, stream>>>((int4*)hist, (int4*)offsets, partials, offsets);
    reorder_kernel<<<(n + 255) / 256, 256, 0, stream>>>(cell, pos, q, hist, sorted, sortedIdx, n);
    tile_scatter_kernel<<<NTILES, 512, 0, stream>>>(sorted, offsets, rmesh);

    fftZfwd<<<1024, 1024, 0, stream>>>(rmesh, mesh);
    fftY<-1><<<9 * 128, 512, 0, stream>>>(mesh);
    fftXG<<<9 * 128, 512, 0, stream>>>(mesh, cell);
    fftY<1><<<9 * 128, 512, 0, stream>>>(mesh);
    fftZinv<<<1024, 1024, 0, stream>>>(mesh, rmesh);

    gather_kernel<<<(n + 255) / 256, 256, 0, stream>>>(sorted, sortedIdx, rmesh, out, n);
}